// Round 3
// baseline (1318.975 us; speedup 1.0000x reference)
//
#include <hip/hip_runtime.h>
#include <cstdint>
#include <cstddef>

constexpr int S = 8192;
constexpr int H = 4096;
constexpr int E = 64;
constexpr int CAP = 256;           // ceil(8192*2/64) = 256
constexpr int KSPLIT = 4;
constexpr int KCHUNK = H / KSPLIT; // 1024
constexpr int BK = 32;
constexpr int BM = 64;
constexpr long long SEC = (long long)S * E * CAP; // 134217728
constexpr long long OUTN = 2 * SEC + 1;           // 268435457 floats
// 512 blocks * 131072 float4 = 268435456 floats = OUTN-1 (tail handled once)
constexpr int F4_PER_BLOCK = 131072;
constexpr int F4_PER_ITER = 16;    // per thread, per k-iter (32 iters * 16 * 256 thr)

typedef float f4_t __attribute__((ext_vector_type(4)));

// ---------------------------------------------------------------------------
// K1: fused fp32 router GEMM + output zero-fill.
// GEMM: logits[s,e] = sum_k A[s,k]*W[e,k]; partials to ws (KSPLIT chunks).
// Fill: interleaved nontemporal float4 zero-stores cover out[0..2^28).
// Stores are issued right after barrier2 so the FMA loop (~1024 cyc) covers
// their completion before the next barrier's vmcnt(0) drain.
// ---------------------------------------------------------------------------
__global__ __launch_bounds__(256)
void k_gemm_fill(const float* __restrict__ A, const float* __restrict__ W,
                 float* __restrict__ part, float* __restrict__ out) {
    __shared__ float As[BK][BM + 4];
    __shared__ float Bs[BK][E + 4];
    const int tid = threadIdx.x;
    const int m0 = blockIdx.x * BM;
    const int kbase = blockIdx.y * KCHUNK;
    const int b = blockIdx.y * gridDim.x + blockIdx.x;  // 0..511
    const int lr = tid >> 3;           // 0..31
    const int lc = (tid & 7) << 2;     // 0,4,..,28
    const int ty = tid >> 4;           // 0..15
    const int tx = tid & 15;           // 0..15

    f4_t* __restrict__ fill = (f4_t*)out + (size_t)b * F4_PER_BLOCK + tid;
    const f4_t z4 = {0.f, 0.f, 0.f, 0.f};

    float acc[4][4];
#pragma unroll
    for (int i = 0; i < 4; ++i)
#pragma unroll
        for (int j = 0; j < 4; ++j) acc[i][j] = 0.f;

    for (int it = 0; it < KCHUNK / BK; ++it) {     // 32 iters
        const int kc = it * BK;
        const float* ap = A + (size_t)(m0 + lr) * H + (kbase + kc + lc);
        const float4 av0 = *(const float4*)ap;
        const float4 av1 = *(const float4*)(ap + (size_t)32 * H);
        const float* bp = W + (size_t)lr * H + (kbase + kc + lc);
        const float4 bv0 = *(const float4*)bp;
        const float4 bv1 = *(const float4*)(bp + (size_t)32 * H);
        __syncthreads();   // drains prev iter's fill stores (fully covered)
        As[lc + 0][lr] = av0.x; As[lc + 1][lr] = av0.y;
        As[lc + 2][lr] = av0.z; As[lc + 3][lr] = av0.w;
        As[lc + 0][lr + 32] = av1.x; As[lc + 1][lr + 32] = av1.y;
        As[lc + 2][lr + 32] = av1.z; As[lc + 3][lr + 32] = av1.w;
        Bs[lc + 0][lr] = bv0.x; Bs[lc + 1][lr] = bv0.y;
        Bs[lc + 2][lr] = bv0.z; Bs[lc + 3][lr] = bv0.w;
        Bs[lc + 0][lr + 32] = bv1.x; Bs[lc + 1][lr + 32] = bv1.y;
        Bs[lc + 2][lr + 32] = bv1.z; Bs[lc + 3][lr + 32] = bv1.w;
        __syncthreads();
        // issue this iter's share of the zero-fill (16 KB/wave in flight)
        f4_t* d = fill + (size_t)it * (F4_PER_ITER * 256);
#pragma unroll
        for (int j = 0; j < F4_PER_ITER; ++j)
            __builtin_nontemporal_store(z4, d + j * 256);
#pragma unroll
        for (int kk = 0; kk < BK; ++kk) {
            const float4 a = *(const float4*)&As[kk][ty * 4];
            const float4 bb = *(const float4*)&Bs[kk][tx * 4];
            acc[0][0] = fmaf(a.x, bb.x, acc[0][0]);
            acc[0][1] = fmaf(a.x, bb.y, acc[0][1]);
            acc[0][2] = fmaf(a.x, bb.z, acc[0][2]);
            acc[0][3] = fmaf(a.x, bb.w, acc[0][3]);
            acc[1][0] = fmaf(a.y, bb.x, acc[1][0]);
            acc[1][1] = fmaf(a.y, bb.y, acc[1][1]);
            acc[1][2] = fmaf(a.y, bb.z, acc[1][2]);
            acc[1][3] = fmaf(a.y, bb.w, acc[1][3]);
            acc[2][0] = fmaf(a.z, bb.x, acc[2][0]);
            acc[2][1] = fmaf(a.z, bb.y, acc[2][1]);
            acc[2][2] = fmaf(a.z, bb.z, acc[2][2]);
            acc[2][3] = fmaf(a.z, bb.w, acc[2][3]);
            acc[3][0] = fmaf(a.w, bb.x, acc[3][0]);
            acc[3][1] = fmaf(a.w, bb.y, acc[3][1]);
            acc[3][2] = fmaf(a.w, bb.z, acc[3][2]);
            acc[3][3] = fmaf(a.w, bb.w, acc[3][3]);
        }
    }
    if (b == 0 && tid == 0) out[(size_t)OUTN - 1] = 0.f;  // ragged tail dword
    float* P = part + (size_t)blockIdx.y * S * E;
#pragma unroll
    for (int i = 0; i < 4; ++i) {
        float4 v = make_float4(acc[i][0], acc[i][1], acc[i][2], acc[i][3]);
        *(float4*)&P[(size_t)(m0 + ty * 4 + i) * E + tx * 4] = v;
    }
}

// ---------------------------------------------------------------------------
// K2: per-token softmax + top-2 (lane = expert). Deterministic KSPLIT reduce.
// ---------------------------------------------------------------------------
__global__ __launch_bounds__(256)
void k_router(const float* __restrict__ part, int* __restrict__ e1a,
              int* __restrict__ e2a, float* __restrict__ g1a,
              float* __restrict__ g2a, float* __restrict__ sumg,
              int* __restrict__ cnt1) {
    const int lane = threadIdx.x & 63;
    const int gw = blockIdx.x * 4 + (threadIdx.x >> 6);
    float lsum = 0.f;
    int lcnt = 0;
    for (int s = gw; s < S; s += 256) {
        const float* p = part + (size_t)s * E + lane;
        float l = p[0] + p[(size_t)S * E] + p[2 * (size_t)S * E]
                + p[3 * (size_t)S * E];
        float m = l;
#pragma unroll
        for (int o = 32; o; o >>= 1) m = fmaxf(m, __shfl_xor(m, o));
        const float ex = __expf(l - m);
        float Z = ex;
#pragma unroll
        for (int o = 32; o; o >>= 1) Z += __shfl_xor(Z, o);
        const float g = ex / Z;
        lsum += g;
        float v1 = g; int i1 = lane;
#pragma unroll
        for (int o = 32; o; o >>= 1) {
            const float ov = __shfl_xor(v1, o);
            const int oi = __shfl_xor(i1, o);
            if (ov > v1 || (ov == v1 && oi < i1)) { v1 = ov; i1 = oi; }
        }
        float v2 = (lane == i1) ? -1.f : g; int i2 = lane;
#pragma unroll
        for (int o = 32; o; o >>= 1) {
            const float ov = __shfl_xor(v2, o);
            const int oi = __shfl_xor(i2, o);
            if (ov > v2 || (ov == v2 && oi < i2)) { v2 = ov; i2 = oi; }
        }
        if (i1 == lane) lcnt++;
        if (lane == 0) {
            e1a[s] = i1; e2a[s] = i2; g1a[s] = v1; g2a[s] = v2;
        }
    }
    atomicAdd(&sumg[lane], lsum);
    atomicAdd(&cnt1[lane], lcnt);
}

// ---------------------------------------------------------------------------
// K3: ordered slot assignment. One wave per expert; ballot+popc = stable rank.
// ---------------------------------------------------------------------------
__global__ __launch_bounds__(64)
void k_assign(const int* __restrict__ e1a, const int* __restrict__ e2a,
              int* __restrict__ slot1a, int* __restrict__ slot2a) {
    const int e = blockIdx.x;
    const int lane = threadIdx.x;
    const unsigned long long below = (1ull << lane) - 1ull;
    int cnt = 0;
    for (int c = 0; c < S; c += 64) {
        const int s = c + lane;
        const bool m = (e1a[s] == e);
        const unsigned long long bal = __ballot(m);
        if (m) {
            const int rank = cnt + __popcll(bal & below);
            slot1a[s] = (rank < CAP) ? rank : -1;
        }
        cnt += __popcll(bal);
    }
    const int total1 = cnt;
    int cnt2 = 0;
    for (int c = 0; c < S; c += 64) {
        const int s = c + lane;
        const bool m = (e2a[s] == e);
        const unsigned long long bal = __ballot(m);
        if (m) {
            const int rank = total1 + cnt2 + __popcll(bal & below);
            slot2a[s] = (rank < CAP) ? rank : -1;
        }
        cnt2 += __popcll(bal);
    }
}

// ---------------------------------------------------------------------------
// K4: scatter the <=2 nonzeros per token into the pre-zeroed output
// (post-drop denom, per reference) + l_aux in block 0's first wave.
// ---------------------------------------------------------------------------
__global__ __launch_bounds__(256)
void k_scatter(const int* __restrict__ e1a, const int* __restrict__ e2a,
               const float* __restrict__ g1a, const float* __restrict__ g2a,
               const int* __restrict__ slot1a, const int* __restrict__ slot2a,
               const float* __restrict__ sumg, const int* __restrict__ cnt1,
               float* __restrict__ out) {
    const int s = blockIdx.x * 256 + threadIdx.x;
    float* comb = out + 1;
    float* mask = out + 1 + (size_t)SEC;
    const int sl1 = slot1a[s], sl2 = slot2a[s];
    const float w1 = (sl1 >= 0) ? g1a[s] : 0.f;
    const float w2 = (sl2 >= 0) ? g2a[s] : 0.f;
    const float denom = fmaxf(w1 + w2, 1.1920928955078125e-07f); // FLT_EPSILON
    if (sl1 >= 0) {
        const size_t off = ((size_t)s * E + e1a[s]) * CAP + sl1;
        comb[off] = w1 / denom;
        mask[off] = 1.f;
    }
    if (sl2 >= 0) {
        const size_t off = ((size_t)s * E + e2a[s]) * CAP + sl2;
        comb[off] = w2 / denom;
        mask[off] = 1.f;
    }
    if (blockIdx.x == 0 && threadIdx.x < 64) {
        const int lane = threadIdx.x;
        float v = sumg[lane] * (float)cnt1[lane];
#pragma unroll
        for (int o = 32; o; o >>= 1) v += __shfl_xor(v, o);
        if (lane == 0) out[0] = v * (float)E / ((float)S * (float)S);
    }
}

extern "C" void kernel_launch(void* const* d_in, const int* in_sizes, int n_in,
                              void* d_out, int out_size, void* d_ws,
                              size_t ws_size, hipStream_t stream) {
    const float* A = (const float*)d_in[0];   // gate_input [S,H] fp32
    const float* W = (const float*)d_in[1];   // gate_weight [E,H] fp32
    float* out = (float*)d_out;

    char* ws = (char*)d_ws;
    float* part = (float*)ws;                                   // 8 MB
    size_t off = (size_t)KSPLIT * S * E * sizeof(float);
    int* e1a = (int*)(ws + off);      off += (size_t)S * 4;
    int* e2a = (int*)(ws + off);      off += (size_t)S * 4;
    float* g1a = (float*)(ws + off);  off += (size_t)S * 4;
    float* g2a = (float*)(ws + off);  off += (size_t)S * 4;
    int* slot1a = (int*)(ws + off);   off += (size_t)S * 4;
    int* slot2a = (int*)(ws + off);   off += (size_t)S * 4;
    float* sumg = (float*)(ws + off); off += (size_t)E * 4;
    int* cnt1 = (int*)(ws + off);     off += (size_t)E * 4;

    hipMemsetAsync(sumg, 0, 2 * (size_t)E * 4, stream);

    k_gemm_fill<<<dim3(S / BM, KSPLIT), 256, 0, stream>>>(A, W, part, out);
    k_router<<<64, 256, 0, stream>>>(part, e1a, e2a, g1a, g2a, sumg, cnt1);
    k_assign<<<E, 64, 0, stream>>>(e1a, e2a, slot1a, slot2a);
    k_scatter<<<S / 256, 256, 0, stream>>>(e1a, e2a, g1a, g2a, slot1a, slot2a,
                                           sumg, cnt1, out);
}

// Round 4
// 1296.211 us; speedup vs baseline: 1.0176x; 1.0176x over previous
//
#include <hip/hip_runtime.h>
#include <cstdint>
#include <cstddef>

constexpr int S = 8192;
constexpr int H = 4096;
constexpr int E = 64;
constexpr int CAP = 256;           // ceil(8192*2/64) = 256
constexpr int KSPLIT = 4;
constexpr int KCHUNK = H / KSPLIT; // 1024
constexpr int BK = 32;
constexpr int BM = 64;
constexpr long long SEC = (long long)S * E * CAP; // 134217728
constexpr long long OUTN = 2 * SEC + 1;           // 268435457 floats
constexpr int NGEMM = (S / BM) * KSPLIT;          // 512 gemm blocks
constexpr int NFILL = 2048;                       // fill blocks
// 2048 fill blocks * 32768 float4 = 2^26 f4 = 2^28 floats = OUTN-1
constexpr int F4_PER_FILL_BLOCK = 32768;          // 128 per thread

typedef float f4_t __attribute__((ext_vector_type(4)));

// ---------------------------------------------------------------------------
// K1: block-specialized launch. Blocks [0,512): fp32 router GEMM writing
// KSPLIT partials to ws. Blocks [512,2560): barrier-free nontemporal zero-fill
// of the 1.07 GB output. Disjoint pipes (VALU vs HBM-write) on shared CUs
// => time ~ max(fill, gemm), not sum. Last fill block also zeroes sumg/cnt1.
// ---------------------------------------------------------------------------
__global__ __launch_bounds__(256)
void k_main(const float* __restrict__ A, const float* __restrict__ W,
            float* __restrict__ part, float* __restrict__ out,
            float* __restrict__ sumg, int* __restrict__ cnt1) {
    __shared__ float As[BK][BM + 4];
    __shared__ float Bs[BK][E + 4];
    const int b = blockIdx.x;
    const int tid = threadIdx.x;

    if (b >= NGEMM) {
        // ---- fill path: no barriers, pure streaming stores ----
        const int fb = b - NGEMM;                  // 0..2047
        f4_t* __restrict__ dst =
            (f4_t*)out + (size_t)fb * F4_PER_FILL_BLOCK + tid;
        const f4_t z4 = {0.f, 0.f, 0.f, 0.f};
#pragma unroll
        for (int j = 0; j < F4_PER_FILL_BLOCK / 256; ++j)   // 128 stores
            __builtin_nontemporal_store(z4, dst + j * 256);
        if (fb == NFILL - 1) {
            if (tid == 0) out[(size_t)OUTN - 1] = 0.f;      // ragged tail
            if (tid < E) sumg[tid] = 0.f;
            else if (tid < 2 * E) cnt1[tid - E] = 0;
        }
        return;
    }

    // ---- gemm path (identical to the verified R1 tile) ----
    const int m0 = (b & (S / BM - 1)) * BM;
    const int kb = b >> 7;                        // kchunk index 0..3
    const int kbase = kb * KCHUNK;
    const int lr = tid >> 3;           // 0..31
    const int lc = (tid & 7) << 2;     // 0,4,..,28
    const int ty = tid >> 4;           // 0..15
    const int tx = tid & 15;           // 0..15

    float acc[4][4];
#pragma unroll
    for (int i = 0; i < 4; ++i)
#pragma unroll
        for (int j = 0; j < 4; ++j) acc[i][j] = 0.f;

    for (int kc = 0; kc < KCHUNK; kc += BK) {
        const float* ap = A + (size_t)(m0 + lr) * H + (kbase + kc + lc);
        const float4 av0 = *(const float4*)ap;
        const float4 av1 = *(const float4*)(ap + (size_t)32 * H);
        const float* bp = W + (size_t)lr * H + (kbase + kc + lc);
        const float4 bv0 = *(const float4*)bp;
        const float4 bv1 = *(const float4*)(bp + (size_t)32 * H);
        __syncthreads();
        As[lc + 0][lr] = av0.x; As[lc + 1][lr] = av0.y;
        As[lc + 2][lr] = av0.z; As[lc + 3][lr] = av0.w;
        As[lc + 0][lr + 32] = av1.x; As[lc + 1][lr + 32] = av1.y;
        As[lc + 2][lr + 32] = av1.z; As[lc + 3][lr + 32] = av1.w;
        Bs[lc + 0][lr] = bv0.x; Bs[lc + 1][lr] = bv0.y;
        Bs[lc + 2][lr] = bv0.z; Bs[lc + 3][lr] = bv0.w;
        Bs[lc + 0][lr + 32] = bv1.x; Bs[lc + 1][lr + 32] = bv1.y;
        Bs[lc + 2][lr + 32] = bv1.z; Bs[lc + 3][lr + 32] = bv1.w;
        __syncthreads();
#pragma unroll
        for (int kk = 0; kk < BK; ++kk) {
            const float4 a = *(const float4*)&As[kk][ty * 4];
            const float4 bb = *(const float4*)&Bs[kk][tx * 4];
            acc[0][0] = fmaf(a.x, bb.x, acc[0][0]);
            acc[0][1] = fmaf(a.x, bb.y, acc[0][1]);
            acc[0][2] = fmaf(a.x, bb.z, acc[0][2]);
            acc[0][3] = fmaf(a.x, bb.w, acc[0][3]);
            acc[1][0] = fmaf(a.y, bb.x, acc[1][0]);
            acc[1][1] = fmaf(a.y, bb.y, acc[1][1]);
            acc[1][2] = fmaf(a.y, bb.z, acc[1][2]);
            acc[1][3] = fmaf(a.y, bb.w, acc[1][3]);
            acc[2][0] = fmaf(a.z, bb.x, acc[2][0]);
            acc[2][1] = fmaf(a.z, bb.y, acc[2][1]);
            acc[2][2] = fmaf(a.z, bb.z, acc[2][2]);
            acc[2][3] = fmaf(a.z, bb.w, acc[2][3]);
            acc[3][0] = fmaf(a.w, bb.x, acc[3][0]);
            acc[3][1] = fmaf(a.w, bb.y, acc[3][1]);
            acc[3][2] = fmaf(a.w, bb.z, acc[3][2]);
            acc[3][3] = fmaf(a.w, bb.w, acc[3][3]);
        }
    }
    float* P = part + (size_t)kb * S * E;
#pragma unroll
    for (int i = 0; i < 4; ++i) {
        float4 v = make_float4(acc[i][0], acc[i][1], acc[i][2], acc[i][3]);
        *(float4*)&P[(size_t)(m0 + ty * 4 + i) * E + tx * 4] = v;
    }
}

// ---------------------------------------------------------------------------
// K2: per-token softmax + top-2 (lane = expert). Deterministic KSPLIT reduce.
// ---------------------------------------------------------------------------
__global__ __launch_bounds__(256)
void k_router(const float* __restrict__ part, int* __restrict__ e1a,
              int* __restrict__ e2a, float* __restrict__ g1a,
              float* __restrict__ g2a, float* __restrict__ sumg,
              int* __restrict__ cnt1) {
    const int lane = threadIdx.x & 63;
    const int gw = blockIdx.x * 4 + (threadIdx.x >> 6);
    float lsum = 0.f;
    int lcnt = 0;
    for (int s = gw; s < S; s += 256) {
        const float* p = part + (size_t)s * E + lane;
        float l = p[0] + p[(size_t)S * E] + p[2 * (size_t)S * E]
                + p[3 * (size_t)S * E];
        float m = l;
#pragma unroll
        for (int o = 32; o; o >>= 1) m = fmaxf(m, __shfl_xor(m, o));
        const float ex = __expf(l - m);
        float Z = ex;
#pragma unroll
        for (int o = 32; o; o >>= 1) Z += __shfl_xor(Z, o);
        const float g = ex / Z;
        lsum += g;
        float v1 = g; int i1 = lane;
#pragma unroll
        for (int o = 32; o; o >>= 1) {
            const float ov = __shfl_xor(v1, o);
            const int oi = __shfl_xor(i1, o);
            if (ov > v1 || (ov == v1 && oi < i1)) { v1 = ov; i1 = oi; }
        }
        float v2 = (lane == i1) ? -1.f : g; int i2 = lane;
#pragma unroll
        for (int o = 32; o; o >>= 1) {
            const float ov = __shfl_xor(v2, o);
            const int oi = __shfl_xor(i2, o);
            if (ov > v2 || (ov == v2 && oi < i2)) { v2 = ov; i2 = oi; }
        }
        if (i1 == lane) lcnt++;
        if (lane == 0) {
            e1a[s] = i1; e2a[s] = i2; g1a[s] = v1; g2a[s] = v2;
        }
    }
    atomicAdd(&sumg[lane], lsum);
    atomicAdd(&cnt1[lane], lcnt);
}

// ---------------------------------------------------------------------------
// K3: ordered slot assignment. One wave per expert; ballot+popc = stable rank.
// ---------------------------------------------------------------------------
__global__ __launch_bounds__(64)
void k_assign(const int* __restrict__ e1a, const int* __restrict__ e2a,
              int* __restrict__ slot1a, int* __restrict__ slot2a) {
    const int e = blockIdx.x;
    const int lane = threadIdx.x;
    const unsigned long long below = (1ull << lane) - 1ull;
    int cnt = 0;
    for (int c = 0; c < S; c += 64) {
        const int s = c + lane;
        const bool m = (e1a[s] == e);
        const unsigned long long bal = __ballot(m);
        if (m) {
            const int rank = cnt + __popcll(bal & below);
            slot1a[s] = (rank < CAP) ? rank : -1;
        }
        cnt += __popcll(bal);
    }
    const int total1 = cnt;
    int cnt2 = 0;
    for (int c = 0; c < S; c += 64) {
        const int s = c + lane;
        const bool m = (e2a[s] == e);
        const unsigned long long bal = __ballot(m);
        if (m) {
            const int rank = total1 + cnt2 + __popcll(bal & below);
            slot2a[s] = (rank < CAP) ? rank : -1;
        }
        cnt2 += __popcll(bal);
    }
}

// ---------------------------------------------------------------------------
// K4: scatter <=2 nonzeros per token (post-drop denom, per reference) into
// the pre-zeroed output + l_aux in block 0's first wave.
// ---------------------------------------------------------------------------
__global__ __launch_bounds__(256)
void k_scatter(const int* __restrict__ e1a, const int* __restrict__ e2a,
               const float* __restrict__ g1a, const float* __restrict__ g2a,
               const int* __restrict__ slot1a, const int* __restrict__ slot2a,
               const float* __restrict__ sumg, const int* __restrict__ cnt1,
               float* __restrict__ out) {
    const int s = blockIdx.x * 256 + threadIdx.x;
    float* comb = out + 1;
    float* mask = out + 1 + (size_t)SEC;
    const int sl1 = slot1a[s], sl2 = slot2a[s];
    const float w1 = (sl1 >= 0) ? g1a[s] : 0.f;
    const float w2 = (sl2 >= 0) ? g2a[s] : 0.f;
    const float denom = fmaxf(w1 + w2, 1.1920928955078125e-07f); // FLT_EPSILON
    if (sl1 >= 0) {
        const size_t off = ((size_t)s * E + e1a[s]) * CAP + sl1;
        comb[off] = w1 / denom;
        mask[off] = 1.f;
    }
    if (sl2 >= 0) {
        const size_t off = ((size_t)s * E + e2a[s]) * CAP + sl2;
        comb[off] = w2 / denom;
        mask[off] = 1.f;
    }
    if (blockIdx.x == 0 && threadIdx.x < 64) {
        const int lane = threadIdx.x;
        float v = sumg[lane] * (float)cnt1[lane];
#pragma unroll
        for (int o = 32; o; o >>= 1) v += __shfl_xor(v, o);
        if (lane == 0) out[0] = v * (float)E / ((float)S * (float)S);
    }
}

extern "C" void kernel_launch(void* const* d_in, const int* in_sizes, int n_in,
                              void* d_out, int out_size, void* d_ws,
                              size_t ws_size, hipStream_t stream) {
    const float* A = (const float*)d_in[0];   // gate_input [S,H] fp32
    const float* W = (const float*)d_in[1];   // gate_weight [E,H] fp32
    float* out = (float*)d_out;

    char* ws = (char*)d_ws;
    float* part = (float*)ws;                                   // 8 MB
    size_t off = (size_t)KSPLIT * S * E * sizeof(float);
    int* e1a = (int*)(ws + off);      off += (size_t)S * 4;
    int* e2a = (int*)(ws + off);      off += (size_t)S * 4;
    float* g1a = (float*)(ws + off);  off += (size_t)S * 4;
    float* g2a = (float*)(ws + off);  off += (size_t)S * 4;
    int* slot1a = (int*)(ws + off);   off += (size_t)S * 4;
    int* slot2a = (int*)(ws + off);   off += (size_t)S * 4;
    float* sumg = (float*)(ws + off); off += (size_t)E * 4;
    int* cnt1 = (int*)(ws + off);     off += (size_t)E * 4;

    k_main<<<NGEMM + NFILL, 256, 0, stream>>>(A, W, part, out, sumg, cnt1);
    k_router<<<64, 256, 0, stream>>>(part, e1a, e2a, g1a, g2a, sumg, cnt1);
    k_assign<<<E, 64, 0, stream>>>(e1a, e2a, slot1a, slot2a);
    k_scatter<<<S / 256, 256, 0, stream>>>(e1a, e2a, g1a, g2a, slot1a, slot2a,
                                           sumg, cnt1, out);
}

// Round 5
// 1272.817 us; speedup vs baseline: 1.0363x; 1.0184x over previous
//
#include <hip/hip_runtime.h>
#include <cstdint>
#include <cstddef>

constexpr int S = 8192;
constexpr int H = 4096;
constexpr int E = 64;
constexpr int CAP = 256;           // ceil(8192*2/64) = 256
constexpr int KSPLIT = 4;
constexpr int KCHUNK = H / KSPLIT; // 1024
constexpr int BK = 32;
constexpr int BM = 64;
constexpr long long SEC = (long long)S * E * CAP; // 134217728

// ---------------------------------------------------------------------------
// K1: fp32 router GEMM  logits[s,e] = sum_k A[s,k] * W[e,k]
// grid (S/BM, KSPLIT), 256 threads. Partials to ws; deterministic reduce in K2.
// fp32 is mandatory: top-2 ordering feeds an order-dependent cumsum — any
// rounding-induced rank flip cascades into wrong slots (absmax 1.0).
// ---------------------------------------------------------------------------
__global__ __launch_bounds__(256)
void k_gemm(const float* __restrict__ A, const float* __restrict__ W,
            float* __restrict__ part) {
    __shared__ float As[BK][BM + 4];
    __shared__ float Bs[BK][E + 4];
    const int tid = threadIdx.x;
    const int m0 = blockIdx.x * BM;
    const int kbase = blockIdx.y * KCHUNK;
    const int lr = tid >> 3;           // 0..31
    const int lc = (tid & 7) << 2;     // 0,4,..,28
    const int ty = tid >> 4;           // 0..15
    const int tx = tid & 15;           // 0..15

    float acc[4][4];
#pragma unroll
    for (int i = 0; i < 4; ++i)
#pragma unroll
        for (int j = 0; j < 4; ++j) acc[i][j] = 0.f;

    for (int kc = 0; kc < KCHUNK; kc += BK) {
        const float* ap = A + (size_t)(m0 + lr) * H + (kbase + kc + lc);
        const float4 av0 = *(const float4*)ap;
        const float4 av1 = *(const float4*)(ap + (size_t)32 * H);
        const float* bp = W + (size_t)lr * H + (kbase + kc + lc);
        const float4 bv0 = *(const float4*)bp;
        const float4 bv1 = *(const float4*)(bp + (size_t)32 * H);
        __syncthreads();
        As[lc + 0][lr] = av0.x; As[lc + 1][lr] = av0.y;
        As[lc + 2][lr] = av0.z; As[lc + 3][lr] = av0.w;
        As[lc + 0][lr + 32] = av1.x; As[lc + 1][lr + 32] = av1.y;
        As[lc + 2][lr + 32] = av1.z; As[lc + 3][lr + 32] = av1.w;
        Bs[lc + 0][lr] = bv0.x; Bs[lc + 1][lr] = bv0.y;
        Bs[lc + 2][lr] = bv0.z; Bs[lc + 3][lr] = bv0.w;
        Bs[lc + 0][lr + 32] = bv1.x; Bs[lc + 1][lr + 32] = bv1.y;
        Bs[lc + 2][lr + 32] = bv1.z; Bs[lc + 3][lr + 32] = bv1.w;
        __syncthreads();
#pragma unroll
        for (int kk = 0; kk < BK; ++kk) {
            const float4 a = *(const float4*)&As[kk][ty * 4];
            const float4 b = *(const float4*)&Bs[kk][tx * 4];
            acc[0][0] = fmaf(a.x, b.x, acc[0][0]);
            acc[0][1] = fmaf(a.x, b.y, acc[0][1]);
            acc[0][2] = fmaf(a.x, b.z, acc[0][2]);
            acc[0][3] = fmaf(a.x, b.w, acc[0][3]);
            acc[1][0] = fmaf(a.y, b.x, acc[1][0]);
            acc[1][1] = fmaf(a.y, b.y, acc[1][1]);
            acc[1][2] = fmaf(a.y, b.z, acc[1][2]);
            acc[1][3] = fmaf(a.y, b.w, acc[1][3]);
            acc[2][0] = fmaf(a.z, b.x, acc[2][0]);
            acc[2][1] = fmaf(a.z, b.y, acc[2][1]);
            acc[2][2] = fmaf(a.z, b.z, acc[2][2]);
            acc[2][3] = fmaf(a.z, b.w, acc[2][3]);
            acc[3][0] = fmaf(a.w, b.x, acc[3][0]);
            acc[3][1] = fmaf(a.w, b.y, acc[3][1]);
            acc[3][2] = fmaf(a.w, b.z, acc[3][2]);
            acc[3][3] = fmaf(a.w, b.w, acc[3][3]);
        }
    }
    float* P = part + (size_t)blockIdx.y * S * E;
#pragma unroll
    for (int i = 0; i < 4; ++i) {
        float4 v = make_float4(acc[i][0], acc[i][1], acc[i][2], acc[i][3]);
        *(float4*)&P[(size_t)(m0 + ty * 4 + i) * E + tx * 4] = v;
    }
}

// ---------------------------------------------------------------------------
// K2: per-token softmax + top-2 (lane = expert). Deterministic KSPLIT reduce.
// ---------------------------------------------------------------------------
__global__ __launch_bounds__(256)
void k_router(const float* __restrict__ part, int* __restrict__ e1a,
              int* __restrict__ e2a, float* __restrict__ g1a,
              float* __restrict__ g2a, float* __restrict__ sumg,
              int* __restrict__ cnt1) {
    const int lane = threadIdx.x & 63;
    const int gw = blockIdx.x * 4 + (threadIdx.x >> 6);
    float lsum = 0.f;
    int lcnt = 0;
    for (int s = gw; s < S; s += 256) {
        const float* p = part + (size_t)s * E + lane;
        float l = p[0] + p[(size_t)S * E] + p[2 * (size_t)S * E]
                + p[3 * (size_t)S * E];
        float m = l;
#pragma unroll
        for (int o = 32; o; o >>= 1) m = fmaxf(m, __shfl_xor(m, o));
        const float ex = __expf(l - m);
        float Z = ex;
#pragma unroll
        for (int o = 32; o; o >>= 1) Z += __shfl_xor(Z, o);
        const float g = ex / Z;
        lsum += g;
        float v1 = g; int i1 = lane;
#pragma unroll
        for (int o = 32; o; o >>= 1) {
            const float ov = __shfl_xor(v1, o);
            const int oi = __shfl_xor(i1, o);
            if (ov > v1 || (ov == v1 && oi < i1)) { v1 = ov; i1 = oi; }
        }
        float v2 = (lane == i1) ? -1.f : g; int i2 = lane;
#pragma unroll
        for (int o = 32; o; o >>= 1) {
            const float ov = __shfl_xor(v2, o);
            const int oi = __shfl_xor(i2, o);
            if (ov > v2 || (ov == v2 && oi < i2)) { v2 = ov; i2 = oi; }
        }
        if (i1 == lane) lcnt++;
        if (lane == 0) {
            e1a[s] = i1; e2a[s] = i2; g1a[s] = v1; g2a[s] = v2;
        }
    }
    atomicAdd(&sumg[lane], lsum);
    atomicAdd(&cnt1[lane], lcnt);
}

// ---------------------------------------------------------------------------
// K3: ordered slot assignment. One wave per expert; ballot+popc = stable rank.
// ---------------------------------------------------------------------------
__global__ __launch_bounds__(64)
void k_assign(const int* __restrict__ e1a, const int* __restrict__ e2a,
              int* __restrict__ slot1a, int* __restrict__ slot2a) {
    const int e = blockIdx.x;
    const int lane = threadIdx.x;
    const unsigned long long below = (1ull << lane) - 1ull;
    int cnt = 0;
    for (int c = 0; c < S; c += 64) {
        const int s = c + lane;
        const bool m = (e1a[s] == e);
        const unsigned long long bal = __ballot(m);
        if (m) {
            const int rank = cnt + __popcll(bal & below);
            slot1a[s] = (rank < CAP) ? rank : -1;
        }
        cnt += __popcll(bal);
    }
    const int total1 = cnt;
    int cnt2 = 0;
    for (int c = 0; c < S; c += 64) {
        const int s = c + lane;
        const bool m = (e2a[s] == e);
        const unsigned long long bal = __ballot(m);
        if (m) {
            const int rank = total1 + cnt2 + __popcll(bal & below);
            slot2a[s] = (rank < CAP) ? rank : -1;
        }
        cnt2 += __popcll(bal);
    }
}

// ---------------------------------------------------------------------------
// K4: scatter <=2 nonzeros per token (post-drop denom, per reference) into
// the pre-zeroed output + l_aux in block 0's first wave.
// ---------------------------------------------------------------------------
__global__ __launch_bounds__(256)
void k_scatter(const int* __restrict__ e1a, const int* __restrict__ e2a,
               const float* __restrict__ g1a, const float* __restrict__ g2a,
               const int* __restrict__ slot1a, const int* __restrict__ slot2a,
               const float* __restrict__ sumg, const int* __restrict__ cnt1,
               float* __restrict__ out) {
    const int s = blockIdx.x * 256 + threadIdx.x;
    float* comb = out + 1;
    float* mask = out + 1 + (size_t)SEC;
    const int sl1 = slot1a[s], sl2 = slot2a[s];
    const float w1 = (sl1 >= 0) ? g1a[s] : 0.f;
    const float w2 = (sl2 >= 0) ? g2a[s] : 0.f;
    const float denom = fmaxf(w1 + w2, 1.1920928955078125e-07f); // FLT_EPSILON
    if (sl1 >= 0) {
        const size_t off = ((size_t)s * E + e1a[s]) * CAP + sl1;
        comb[off] = w1 / denom;
        mask[off] = 1.f;
    }
    if (sl2 >= 0) {
        const size_t off = ((size_t)s * E + e2a[s]) * CAP + sl2;
        comb[off] = w2 / denom;
        mask[off] = 1.f;
    }
    if (blockIdx.x == 0 && threadIdx.x < 64) {
        const int lane = threadIdx.x;
        float v = sumg[lane] * (float)cnt1[lane];
#pragma unroll
        for (int o = 32; o; o >>= 1) v += __shfl_xor(v, o);
        if (lane == 0) out[0] = v * (float)E / ((float)S * (float)S);
    }
}

extern "C" void kernel_launch(void* const* d_in, const int* in_sizes, int n_in,
                              void* d_out, int out_size, void* d_ws,
                              size_t ws_size, hipStream_t stream) {
    const float* A = (const float*)d_in[0];   // gate_input [S,H] fp32
    const float* W = (const float*)d_in[1];   // gate_weight [E,H] fp32
    float* out = (float*)d_out;

    char* ws = (char*)d_ws;
    float* part = (float*)ws;                                   // 8 MB
    size_t off = (size_t)KSPLIT * S * E * sizeof(float);
    int* e1a = (int*)(ws + off);      off += (size_t)S * 4;
    int* e2a = (int*)(ws + off);      off += (size_t)S * 4;
    float* g1a = (float*)(ws + off);  off += (size_t)S * 4;
    float* g2a = (float*)(ws + off);  off += (size_t)S * 4;
    int* slot1a = (int*)(ws + off);   off += (size_t)S * 4;
    int* slot2a = (int*)(ws + off);   off += (size_t)S * 4;
    float* sumg = (float*)(ws + off); off += (size_t)E * 4;
    int* cnt1 = (int*)(ws + off);     off += (size_t)E * 4;

    // rocclr fill (measured 6.2 TB/s) beats every hand-rolled fill we tried
    // (R2 dword-writer +33 µs, R3 barrier-coupled +43, R4 specialized +20).
    hipMemsetAsync(sumg, 0, 2 * (size_t)E * 4, stream);
    hipMemsetAsync(d_out, 0, (size_t)out_size * sizeof(float), stream);

    k_gemm<<<dim3(S / BM, KSPLIT), 256, 0, stream>>>(A, W, part);
    k_router<<<64, 256, 0, stream>>>(part, e1a, e2a, g1a, g2a, sumg, cnt1);
    k_assign<<<E, 64, 0, stream>>>(e1a, e2a, slot1a, slot2a);
    k_scatter<<<S / 256, 256, 0, stream>>>(e1a, e2a, g1a, g2a, slot1a, slot2a,
                                           sumg, cnt1, out);
}